// Round 9
// baseline (1148.778 us; speedup 1.0000x reference)
//
#include <hip/hip_runtime.h>
#include <math.h>

// ---------------------------------------------------------------------------
// InvKin, fp32-VALU pipeline with bf16 z-materialization (R8).
// R5-R7 evidence: f32x2 h[64] (512 B alloca) is NEVER promoted to registers
// (spill -> ~470 MB phantom HBM writes) regardless of launch bounds; R4's
// float h[64] (256 B) promoted fine. R8 keeps the 2-rows/thread weight
// amortization but stores h as TWO scalar arrays hA[64]/hB[64] (256 B each,
// the known-promoting shape). Dual-row dots share one weight load across two
// fmaf chains. waves_per_eu(2,2) retained so ~180 VGPRs are legal.
//   P1 k_stats_x : x second moments (layer-1 BN stats analytic)
//   P2 k_fin1    : fold BN1 -> fp32 W1p[64][3] + c1[64]
//   P3 k_z2      : h1 -> raw z2 -> bf16 zbuf[B][64]   (2 rows/thread)
//   P4 k_colstats: coalesced per-unit sum/ssq of zbuf
//   P5 k_fin_bn  : s2,c2
//   P6 k_z3      : h2 = relu(s2*z2+c2); z3 = W3 h2 + b3 in place
//   P7 k_colstats: stats of z3
//   P8 k_fin_bn  : s3,c3
//   P9 k_final   : h3 -> head -> closed-form FK -> out
// Fallback path (small ws): exact R1 kernel set (verified PASS).
// ---------------------------------------------------------------------------

static constexpr float kEps = 1e-5f;

#define HEAVY_BOUNDS __launch_bounds__(256) __attribute__((amdgpu_waves_per_eu(2, 2)))

// shared ws fp32 indices (both paths)
#define WS_STAT9 0
#define WS_SUM2  16
#define WS_SSQ2  80
#define WS_SUM3  144
#define WS_SSQ3  208
#define WS_W1P   288    // [64][3] fp32 (BN1-folded)
#define WS_C1    480    // [64]
// fast path only
#define FP_S2    8192
#define FP_C2    8256
#define FP_S3    8320
#define FP_C3    8384
// fallback (R1) only — may overlap FP_* since only one path ever runs
#define RC_W2P   544
#define RC_C2    4640
#define RC_W3P   4704
#define RC_C3    8800
// z buffer: byte offset 65536 (ushort index 32768)
#define ZB_U16   32768

__device__ __forceinline__ unsigned short f2bf(float f) {
  unsigned u = __builtin_bit_cast(unsigned, f);
  u += 0x7fffu + ((u >> 16) & 1u);
  return (unsigned short)(u >> 16);
}
__device__ __forceinline__ unsigned packbf2(float a, float b) {
  return (unsigned)f2bf(a) | ((unsigned)f2bf(b) << 16);
}
__device__ __forceinline__ void unpack2(unsigned w, float& lo, float& hi) {
  lo = __builtin_bit_cast(float, w << 16);
  hi = __builtin_bit_cast(float, w & 0xffff0000u);
}
__device__ __forceinline__ float bfbits(unsigned short s) {
  unsigned u = ((unsigned)s) << 16;
  return __builtin_bit_cast(float, u);
}

__device__ __forceinline__ float wred64(float v) {
  v += __shfl_xor(v, 32, 64);
  v += __shfl_xor(v, 16, 64);
  v += __shfl_xor(v, 8, 64);
  v += __shfl_xor(v, 4, 64);
  v += __shfl_xor(v, 2, 64);
  v += __shfl_xor(v, 1, 64);
  return v;
}

// dual-row dot: one weight load feeds two fmaf chains
__device__ __forceinline__ void dot64d(const float* __restrict__ wr,
                                       const float* __restrict__ hA,
                                       const float* __restrict__ hB,
                                       float& oA, float& oB) {
  float a0 = 0.f, a1 = 0.f, b0 = 0.f, b1 = 0.f;
#pragma unroll
  for (int k = 0; k < 64; k += 2) {
    float w0 = wr[k], w1 = wr[k + 1];
    a0 = fmaf(w0, hA[k], a0);
    b0 = fmaf(w0, hB[k], b0);
    a1 = fmaf(w1, hA[k + 1], a1);
    b1 = fmaf(w1, hB[k + 1], b1);
  }
  oA = a0 + a1;
  oB = b0 + b1;
}

__device__ __forceinline__ float dot64(const float* __restrict__ wr,
                                       const float hin[64]) {
  float a0 = 0.f, a1 = 0.f, a2 = 0.f, a3 = 0.f;
#pragma unroll
  for (int k = 0; k < 64; k += 4) {
    a0 = fmaf(wr[k + 0], hin[k + 0], a0);
    a1 = fmaf(wr[k + 1], hin[k + 1], a1);
    a2 = fmaf(wr[k + 2], hin[k + 2], a2);
    a3 = fmaf(wr[k + 3], hin[k + 3], a3);
  }
  return (a0 + a1) + (a2 + a3);
}

// ---- P1: x second moments (shared) ---------------------------------------
__global__ void __launch_bounds__(256) k_stats_x(const float* __restrict__ x,
                                                 float* __restrict__ ws, int B) {
  int tid = blockIdx.x * 256 + threadIdx.x;
  int nt = gridDim.x * 256;
  float s0 = 0.f, s1 = 0.f, s2 = 0.f;
  float q00 = 0.f, q01 = 0.f, q02 = 0.f, q11 = 0.f, q12 = 0.f, q22 = 0.f;
  for (int r = tid; r < B; r += nt) {
    float x0 = x[3 * r], x1 = x[3 * r + 1], x2 = x[3 * r + 2];
    s0 += x0; s1 += x1; s2 += x2;
    q00 = fmaf(x0, x0, q00); q01 = fmaf(x0, x1, q01); q02 = fmaf(x0, x2, q02);
    q11 = fmaf(x1, x1, q11); q12 = fmaf(x1, x2, q12); q22 = fmaf(x2, x2, q22);
  }
  s0 = wred64(s0); s1 = wred64(s1); s2 = wred64(s2);
  q00 = wred64(q00); q01 = wred64(q01); q02 = wred64(q02);
  q11 = wred64(q11); q12 = wred64(q12); q22 = wred64(q22);
  __shared__ float part[9];
  if (threadIdx.x < 9) part[threadIdx.x] = 0.f;
  __syncthreads();
  if ((threadIdx.x & 63) == 0) {
    atomicAdd(&part[0], s0); atomicAdd(&part[1], s1); atomicAdd(&part[2], s2);
    atomicAdd(&part[3], q00); atomicAdd(&part[4], q01); atomicAdd(&part[5], q02);
    atomicAdd(&part[6], q11); atomicAdd(&part[7], q12); atomicAdd(&part[8], q22);
  }
  __syncthreads();
  if (threadIdx.x < 9) atomicAdd(&ws[WS_STAT9 + threadIdx.x], part[threadIdx.x]);
}

// ---- P2: fold BN1 (shared) ------------------------------------------------
__global__ void k_fin1(const float* __restrict__ W1, const float* __restrict__ b1,
                       const float* __restrict__ g1, const float* __restrict__ be1,
                       float* __restrict__ ws, int B) {
  int j = threadIdx.x;  // 64
  float inv = 1.0f / (float)B;
  float ex0 = ws[0] * inv, ex1 = ws[1] * inv, ex2 = ws[2] * inv;
  float c00 = ws[3] * inv - ex0 * ex0;
  float c01 = ws[4] * inv - ex0 * ex1;
  float c02 = ws[5] * inv - ex0 * ex2;
  float c11 = ws[6] * inv - ex1 * ex1;
  float c12 = ws[7] * inv - ex1 * ex2;
  float c22 = ws[8] * inv - ex2 * ex2;
  float w0 = W1[3 * j], w1 = W1[3 * j + 1], w2 = W1[3 * j + 2];
  float mean = w0 * ex0 + w1 * ex1 + w2 * ex2 + b1[j];
  float var = w0 * w0 * c00 + w1 * w1 * c11 + w2 * w2 * c22 +
              2.f * (w0 * w1 * c01 + w0 * w2 * c02 + w1 * w2 * c12);
  float s = g1[j] * rsqrtf(var + kEps);
  ws[WS_W1P + 3 * j + 0] = s * w0;
  ws[WS_W1P + 3 * j + 1] = s * w1;
  ws[WS_W1P + 3 * j + 2] = s * w2;
  ws[WS_C1 + j] = fmaf(s, b1[j] - mean, be1[j]);
}

// =========================== FAST PATH =====================================

// ---- P3: z2 = W2 h1 + b2 -> bf16 zbuf (2 rows/thread) --------------------
__global__ void HEAVY_BOUNDS k_z2(const float* __restrict__ x,
                                  const float* __restrict__ W2,
                                  const float* __restrict__ b2,
                                  const float* __restrict__ ws,
                                  unsigned short* __restrict__ zb, int B) {
  const float* W1p = ws + WS_W1P;
  const float* c1 = ws + WS_C1;
  int tid = blockIdx.x * 256 + threadIdx.x;
  int nt = gridDim.x * 256;
  int npair = (B + 1) >> 1;
  for (int p = tid; p < npair; p += nt) {
    int r0 = 2 * p;
    int r1 = (r0 + 1 < B) ? (r0 + 1) : r0;
    float xA0 = x[3 * r0], xA1 = x[3 * r0 + 1], xA2 = x[3 * r0 + 2];
    float xB0 = x[3 * r1], xB1 = x[3 * r1 + 1], xB2 = x[3 * r1 + 2];
    float hA[64], hB[64];
#pragma unroll
    for (int k = 0; k < 64; ++k) {
      float w0 = W1p[3 * k + 0], w1 = W1p[3 * k + 1], w2 = W1p[3 * k + 2], c = c1[k];
      float zA = fmaf(w2, xA2, fmaf(w1, xA1, fmaf(w0, xA0, c)));
      float zB = fmaf(w2, xB2, fmaf(w1, xB1, fmaf(w0, xB0, c)));
      hA[k] = fmaxf(zA, 0.f);
      hB[k] = fmaxf(zB, 0.f);
    }
    uint4* zrA = (uint4*)(zb + (size_t)r0 * 64);
    uint4* zrB = (uint4*)(zb + (size_t)r1 * 64);
#pragma unroll 1
    for (int jb = 0; jb < 8; ++jb) {
      float zA[8], zB[8];
#pragma unroll
      for (int u = 0; u < 8; ++u) {
        int j = jb * 8 + u;
        float a, b;
        dot64d(W2 + j * 64, hA, hB, a, b);
        zA[u] = a + b2[j];
        zB[u] = b + b2[j];
      }
      uint4 oA, oB;
      oA.x = packbf2(zA[0], zA[1]); oA.y = packbf2(zA[2], zA[3]);
      oA.z = packbf2(zA[4], zA[5]); oA.w = packbf2(zA[6], zA[7]);
      oB.x = packbf2(zB[0], zB[1]); oB.y = packbf2(zB[2], zB[3]);
      oB.z = packbf2(zB[4], zB[5]); oB.w = packbf2(zB[6], zB[7]);
      zrA[jb] = oA;
      zrB[jb] = oB;
    }
  }
}

// ---- P4/P7: coalesced per-unit sum/ssq of zbuf ---------------------------
__global__ void __launch_bounds__(256) k_colstats(const unsigned short* __restrict__ zb,
                                                  float* __restrict__ sumg,
                                                  float* __restrict__ ssqg, int B) {
  int u = threadIdx.x & 63;
  int rloc = threadIdx.x >> 6;              // 0..3
  int rstep = gridDim.x * 4;
  float accS = 0.f, accQ = 0.f;
  for (int r = blockIdx.x * 4 + rloc; r < B; r += rstep) {
    float z = bfbits(zb[(size_t)r * 64 + u]);
    accS += z;
    accQ = fmaf(z, z, accQ);
  }
  __shared__ float sS[64], sQ[64];
  if (threadIdx.x < 64) { sS[threadIdx.x] = 0.f; sQ[threadIdx.x] = 0.f; }
  __syncthreads();
  atomicAdd(&sS[u], accS);
  atomicAdd(&sQ[u], accQ);
  __syncthreads();
  if (threadIdx.x < 64) {
    atomicAdd(&sumg[threadIdx.x], sS[threadIdx.x]);
    atomicAdd(&ssqg[threadIdx.x], sQ[threadIdx.x]);
  }
}

// ---- P5/P8: BN scale/shift only ------------------------------------------
__global__ void k_fin_bn(const float* __restrict__ sum, const float* __restrict__ ssq,
                         const float* __restrict__ g, const float* __restrict__ be,
                         float* __restrict__ sOut, float* __restrict__ cOut, int B) {
  int j = threadIdx.x;  // 64
  float inv = 1.0f / (float)B;
  float mean = sum[j] * inv;
  float var = ssq[j] * inv - mean * mean;
  float s = g[j] * rsqrtf(var + kEps);
  sOut[j] = s;
  cOut[j] = fmaf(-s, mean, be[j]);
}

// ---- P6: z3 = W3 relu(s2*z2+c2) + b3, in place (2 rows/thread) -----------
__global__ void HEAVY_BOUNDS k_z3(const float* __restrict__ W3,
                                  const float* __restrict__ b3,
                                  const float* __restrict__ ws,
                                  unsigned short* __restrict__ zb, int B) {
  const float* s2 = ws + FP_S2;
  const float* c2 = ws + FP_C2;
  int tid = blockIdx.x * 256 + threadIdx.x;
  int nt = gridDim.x * 256;
  int npair = (B + 1) >> 1;
  for (int p = tid; p < npair; p += nt) {
    int r0 = 2 * p;
    int r1 = (r0 + 1 < B) ? (r0 + 1) : r0;
    uint4* zrA = (uint4*)(zb + (size_t)r0 * 64);
    uint4* zrB = (uint4*)(zb + (size_t)r1 * 64);
    float hA[64], hB[64];
#pragma unroll
    for (int jb = 0; jb < 8; ++jb) {
      uint4 vA = zrA[jb], vB = zrB[jb];
      int k = jb * 8;
      unpack2(vA.x, hA[k + 0], hA[k + 1]);
      unpack2(vA.y, hA[k + 2], hA[k + 3]);
      unpack2(vA.z, hA[k + 4], hA[k + 5]);
      unpack2(vA.w, hA[k + 6], hA[k + 7]);
      unpack2(vB.x, hB[k + 0], hB[k + 1]);
      unpack2(vB.y, hB[k + 2], hB[k + 3]);
      unpack2(vB.z, hB[k + 4], hB[k + 5]);
      unpack2(vB.w, hB[k + 6], hB[k + 7]);
    }
#pragma unroll
    for (int k = 0; k < 64; ++k) {
      float s = s2[k], c = c2[k];
      hA[k] = fmaxf(fmaf(s, hA[k], c), 0.f);
      hB[k] = fmaxf(fmaf(s, hB[k], c), 0.f);
    }
#pragma unroll 1
    for (int jb = 0; jb < 8; ++jb) {
      float zA[8], zB[8];
#pragma unroll
      for (int u = 0; u < 8; ++u) {
        int j = jb * 8 + u;
        float a, b;
        dot64d(W3 + j * 64, hA, hB, a, b);
        zA[u] = a + b3[j];
        zB[u] = b + b3[j];
      }
      uint4 oA, oB;
      oA.x = packbf2(zA[0], zA[1]); oA.y = packbf2(zA[2], zA[3]);
      oA.z = packbf2(zA[4], zA[5]); oA.w = packbf2(zA[6], zA[7]);
      oB.x = packbf2(zB[0], zB[1]); oB.y = packbf2(zB[2], zB[3]);
      oB.z = packbf2(zB[4], zB[5]); oB.w = packbf2(zB[6], zB[7]);
      zrA[jb] = oA;
      zrB[jb] = oB;
    }
  }
}

// ---- P9: h3 -> head -> FK -> out (2 rows/thread) --------------------------
__global__ void HEAVY_BOUNDS k_final_fast(const unsigned short* __restrict__ zb,
                                          const float* __restrict__ W4,
                                          const float* __restrict__ b4,
                                          const float* __restrict__ ws,
                                          float* __restrict__ out, int B) {
  const float* s3 = ws + FP_S3;
  const float* c3 = ws + FP_C3;
  int tid = blockIdx.x * 256 + threadIdx.x;
  int nt = gridDim.x * 256;
  int npair = (B + 1) >> 1;
  for (int p = tid; p < npair; p += nt) {
    int r0 = 2 * p;
    int r1 = (r0 + 1 < B) ? (r0 + 1) : r0;
    const uint4* zrA = (const uint4*)(zb + (size_t)r0 * 64);
    const uint4* zrB = (const uint4*)(zb + (size_t)r1 * 64);
    float hA[64], hB[64];
#pragma unroll
    for (int jb = 0; jb < 8; ++jb) {
      uint4 vA = zrA[jb], vB = zrB[jb];
      int k = jb * 8;
      unpack2(vA.x, hA[k + 0], hA[k + 1]);
      unpack2(vA.y, hA[k + 2], hA[k + 3]);
      unpack2(vA.z, hA[k + 4], hA[k + 5]);
      unpack2(vA.w, hA[k + 6], hA[k + 7]);
      unpack2(vB.x, hB[k + 0], hB[k + 1]);
      unpack2(vB.y, hB[k + 2], hB[k + 3]);
      unpack2(vB.z, hB[k + 4], hB[k + 5]);
      unpack2(vB.w, hB[k + 6], hB[k + 7]);
    }
#pragma unroll
    for (int k = 0; k < 64; ++k) {
      float s = s3[k], c = c3[k];
      hA[k] = fmaxf(fmaf(s, hA[k], c), 0.f);
      hB[k] = fmaxf(fmaf(s, hB[k], c), 0.f);
    }
    float t0A, t0B, t1A, t1B, t2A, t2B;
    dot64d(W4, hA, hB, t0A, t0B);
    dot64d(W4 + 64, hA, hB, t1A, t1B);
    dot64d(W4 + 128, hA, hB, t2A, t2B);
    t0A += b4[0]; t0B += b4[0];
    t1A += b4[1]; t1B += b4[1];
    t2A += b4[2]; t2B += b4[2];
    {
      out[3 * r0 + 0] = t0A;
      out[3 * r0 + 1] = t1A;
      out[3 * r0 + 2] = t2A;
      float s0, c0v, s1, c1v, s12, c12;
      sincosf(t0A, &s0, &c0v);
      sincosf(t1A, &s1, &c1v);
      sincosf(t1A + t2A, &s12, &c12);
      float A = fmaf(0.115f, c12, 0.12f * c1v);
      size_t o2 = (size_t)3 * B + 3 * r0;
      out[o2 + 0] = c0v * A;
      out[o2 + 1] = s0 * A;
      out[o2 + 2] = fmaf(0.115f, s12, 0.12f * s1);
    }
    if (r1 != r0) {
      out[3 * r1 + 0] = t0B;
      out[3 * r1 + 1] = t1B;
      out[3 * r1 + 2] = t2B;
      float s0, c0v, s1, c1v, s12, c12;
      sincosf(t0B, &s0, &c0v);
      sincosf(t1B, &s1, &c1v);
      sincosf(t1B + t2B, &s12, &c12);
      float A = fmaf(0.115f, c12, 0.12f * c1v);
      size_t o2 = (size_t)3 * B + 3 * r1;
      out[o2 + 0] = c0v * A;
      out[o2 + 1] = s0 * A;
      out[o2 + 2] = fmaf(0.115f, s12, 0.12f * s1);
    }
  }
}

// ========================= FALLBACK (R1, verified) =========================

__device__ __forceinline__ void layer1_eval(const float* __restrict__ W1p,
                                            const float* __restrict__ c1,
                                            float x0, float x1, float x2,
                                            float h[64]) {
#pragma unroll
  for (int j = 0; j < 64; ++j) {
    float z = fmaf(W1p[3 * j + 2], x2,
               fmaf(W1p[3 * j + 1], x1, fmaf(W1p[3 * j], x0, c1[j])));
    h[j] = fmaxf(z, 0.f);
  }
}

__device__ __forceinline__ void dense_relu_rc(const float* __restrict__ Wp,
                                              const float* __restrict__ c,
                                              const float hin[64], float hout[64]) {
#pragma unroll
  for (int j = 0; j < 64; ++j)
    hout[j] = fmaxf(dot64(Wp + j * 64, hin) + c[j], 0.f);
}

__device__ __forceinline__ void dense_stats_rc(const float* __restrict__ W,
                                               const float* __restrict__ b,
                                               const float hin[64], int lane,
                                               float valid, float& accS, float& accQ) {
#pragma unroll 1
  for (int j = 0; j < 64; ++j) {
    float z = (dot64(W + j * 64, hin) + b[j]) * valid;
    float rs = wred64(z);
    float rq = wred64(z * z);
    accS += (lane == j) ? rs : 0.f;
    accQ += (lane == j) ? rq : 0.f;
  }
}

__device__ __forceinline__ void block_combine_rc(float accS, float accQ,
                                                 float* __restrict__ sumg,
                                                 float* __restrict__ ssqg) {
  __shared__ float sS[256], sQ[256];
  sS[threadIdx.x] = accS;
  sQ[threadIdx.x] = accQ;
  __syncthreads();
  if (threadIdx.x < 64) {
    float S = sS[threadIdx.x] + sS[threadIdx.x + 64] + sS[threadIdx.x + 128] + sS[threadIdx.x + 192];
    float Q = sQ[threadIdx.x] + sQ[threadIdx.x + 64] + sQ[threadIdx.x + 128] + sQ[threadIdx.x + 192];
    atomicAdd(&sumg[threadIdx.x], S);
    atomicAdd(&ssqg[threadIdx.x], Q);
  }
}

__global__ void __launch_bounds__(256) k_stats2_rc(const float* __restrict__ x,
                                                   const float* __restrict__ W2,
                                                   const float* __restrict__ b2,
                                                   float* __restrict__ ws, int B) {
  const float* W1p = ws + WS_W1P;
  const float* c1 = ws + WS_C1;
  int tid = blockIdx.x * 256 + threadIdx.x;
  int nt = gridDim.x * 256;
  int lane = threadIdx.x & 63;
  float accS = 0.f, accQ = 0.f;
  int iters = (B + nt - 1) / nt;
  for (int it = 0; it < iters; ++it) {
    int r = tid + it * nt;
    float valid = (r < B) ? 1.f : 0.f;
    int rc = (r < B) ? r : (B - 1);
    float h1[64];
    layer1_eval(W1p, c1, x[3 * rc], x[3 * rc + 1], x[3 * rc + 2], h1);
    dense_stats_rc(W2, b2, h1, lane, valid, accS, accQ);
  }
  block_combine_rc(accS, accQ, ws + WS_SUM2, ws + WS_SSQ2);
}

__global__ void k_fin_dense_rc(const float* __restrict__ W, const float* __restrict__ b,
                               const float* __restrict__ g, const float* __restrict__ be,
                               const float* __restrict__ sum, const float* __restrict__ ssq,
                               float* __restrict__ Wp, float* __restrict__ cc, int B) {
  int j = threadIdx.x;
  float inv = 1.0f / (float)B;
  float mean = sum[j] * inv;
  float var = ssq[j] * inv - mean * mean;
  float s = g[j] * rsqrtf(var + kEps);
  for (int k = 0; k < 64; ++k) Wp[j * 64 + k] = s * W[j * 64 + k];
  cc[j] = fmaf(s, b[j] - mean, be[j]);
}

__global__ void __launch_bounds__(256) k_stats3_rc(const float* __restrict__ x,
                                                   const float* __restrict__ W3,
                                                   const float* __restrict__ b3,
                                                   float* __restrict__ ws, int B) {
  const float* W1p = ws + WS_W1P;
  const float* c1 = ws + WS_C1;
  const float* W2p = ws + RC_W2P;
  const float* c2 = ws + RC_C2;
  int tid = blockIdx.x * 256 + threadIdx.x;
  int nt = gridDim.x * 256;
  int lane = threadIdx.x & 63;
  float accS = 0.f, accQ = 0.f;
  int iters = (B + nt - 1) / nt;
  for (int it = 0; it < iters; ++it) {
    int r = tid + it * nt;
    float valid = (r < B) ? 1.f : 0.f;
    int rc = (r < B) ? r : (B - 1);
    float h1[64], h2[64];
    layer1_eval(W1p, c1, x[3 * rc], x[3 * rc + 1], x[3 * rc + 2], h1);
    dense_relu_rc(W2p, c2, h1, h2);
    dense_stats_rc(W3, b3, h2, lane, valid, accS, accQ);
  }
  block_combine_rc(accS, accQ, ws + WS_SUM3, ws + WS_SSQ3);
}

__global__ void __launch_bounds__(256) k_final_rc(const float* __restrict__ x,
                                                  const float* __restrict__ W4,
                                                  const float* __restrict__ b4,
                                                  const float* __restrict__ ws,
                                                  float* __restrict__ out, int B) {
  const float* W1p = ws + WS_W1P;
  const float* c1 = ws + WS_C1;
  const float* W2p = ws + RC_W2P;
  const float* c2 = ws + RC_C2;
  const float* W3p = ws + RC_W3P;
  const float* c3 = ws + RC_C3;
  int tid = blockIdx.x * 256 + threadIdx.x;
  int nt = gridDim.x * 256;
  for (int r = tid; r < B; r += nt) {
    float h1[64], h2[64];
    layer1_eval(W1p, c1, x[3 * r], x[3 * r + 1], x[3 * r + 2], h1);
    dense_relu_rc(W2p, c2, h1, h2);
    float t0 = b4[0], t1 = b4[1], t2 = b4[2];
#pragma unroll 1
    for (int j = 0; j < 64; ++j) {
      float h3 = fmaxf(dot64(W3p + j * 64, h2) + c3[j], 0.f);
      t0 = fmaf(W4[j], h3, t0);
      t1 = fmaf(W4[64 + j], h3, t1);
      t2 = fmaf(W4[128 + j], h3, t2);
    }
    out[3 * r + 0] = t0;
    out[3 * r + 1] = t1;
    out[3 * r + 2] = t2;
    float s0, c0v, s1, c1v, s12, c12;
    sincosf(t0, &s0, &c0v);
    sincosf(t1, &s1, &c1v);
    sincosf(t1 + t2, &s12, &c12);
    float A = fmaf(0.115f, c12, 0.12f * c1v);
    size_t o2 = (size_t)3 * B + 3 * r;
    out[o2 + 0] = c0v * A;
    out[o2 + 1] = s0 * A;
    out[o2 + 2] = fmaf(0.115f, s12, 0.12f * s1);
  }
}

// ===========================================================================

extern "C" void kernel_launch(void* const* d_in, const int* in_sizes, int n_in,
                              void* d_out, int out_size, void* d_ws, size_t ws_size,
                              hipStream_t stream) {
  const float* x = (const float*)d_in[0];
  const float* W1 = (const float*)d_in[1];
  const float* b1 = (const float*)d_in[2];
  const float* g1 = (const float*)d_in[3];
  const float* be1 = (const float*)d_in[4];
  const float* W2 = (const float*)d_in[5];
  const float* b2 = (const float*)d_in[6];
  const float* g2 = (const float*)d_in[7];
  const float* be2 = (const float*)d_in[8];
  const float* W3 = (const float*)d_in[9];
  const float* b3 = (const float*)d_in[10];
  const float* g3 = (const float*)d_in[11];
  const float* be3 = (const float*)d_in[12];
  const float* W4 = (const float*)d_in[13];
  const float* b4 = (const float*)d_in[14];
  float* ws = (float*)d_ws;
  float* out = (float*)d_out;
  int B = in_sizes[0] / 3;

  hipMemsetAsync(d_ws, 0, 272 * sizeof(float), stream);

  const int blocks = 1024, thr = 256;
  const int zblocks = 2048;
  size_t need = 65536 + (size_t)B * 64 * 2;

  k_stats_x<<<blocks, thr, 0, stream>>>(x, ws, B);
  k_fin1<<<1, 64, 0, stream>>>(W1, b1, g1, be1, ws, B);

  if (ws_size >= need) {
    unsigned short* zb = (unsigned short*)ws + ZB_U16;
    k_z2<<<zblocks, thr, 0, stream>>>(x, W2, b2, ws, zb, B);
    k_colstats<<<blocks, thr, 0, stream>>>(zb, ws + WS_SUM2, ws + WS_SSQ2, B);
    k_fin_bn<<<1, 64, 0, stream>>>(ws + WS_SUM2, ws + WS_SSQ2, g2, be2,
                                   ws + FP_S2, ws + FP_C2, B);
    k_z3<<<zblocks, thr, 0, stream>>>(W3, b3, ws, zb, B);
    k_colstats<<<blocks, thr, 0, stream>>>(zb, ws + WS_SUM3, ws + WS_SSQ3, B);
    k_fin_bn<<<1, 64, 0, stream>>>(ws + WS_SUM3, ws + WS_SSQ3, g3, be3,
                                   ws + FP_S3, ws + FP_C3, B);
    k_final_fast<<<zblocks, thr, 0, stream>>>(zb, W4, b4, ws, out, B);
  } else {
    k_stats2_rc<<<blocks, thr, 0, stream>>>(x, W2, b2, ws, B);
    k_fin_dense_rc<<<1, 64, 0, stream>>>(W2, b2, g2, be2, ws + WS_SUM2, ws + WS_SSQ2,
                                         ws + RC_W2P, ws + RC_C2, B);
    k_stats3_rc<<<blocks, thr, 0, stream>>>(x, W3, b3, ws, B);
    k_fin_dense_rc<<<1, 64, 0, stream>>>(W3, b3, g3, be3, ws + WS_SUM3, ws + WS_SSQ3,
                                         ws + RC_W3P, ws + RC_C3, B);
    k_final_rc<<<blocks, thr, 0, stream>>>(x, W4, b4, ws, out, B);
  }
}